// Round 7
// baseline (846.059 us; speedup 1.0000x reference)
//
#include <hip/hip_runtime.h>
#include <hip/hip_cooperative_groups.h>
#include <math.h>

namespace cg = cooperative_groups;

// Problem sizes (fixed by reference)
#define D   2048
#define H   2048
#define K0  16
#define KJ  8

// Skip threshold: c_leaf[k] = assign[k]*tanh(.), |tanh|<=1 -> dropping
// assign[k] < 1e-7 perturbs outputs by <= ~2e-4 << 0.16 threshold.
#define SKIP_THR 1e-7f

#define NBLK 512   // cooperative grid: 2 blocks/CU guaranteed by launch_bounds

// ---- workspace layout (floats), shared by both paths ----
#define WS_SQ     0         // [16] squared distances (fused) / assign (fallback)
#define WS_GATE   64        // [16][8]
#define WS_CLEAF  256       // [16][2048]
#define WS_PLEAF  33024     // [32 dc][16 k][2048 h]
#define WS_PNL    1081600   // [16 hc][8 j][16 k][2048 g]
#define WS_CNL    5275904   // [8][2048]
#define WS_PROOT  5292288   // [32 gc][8 j][2048 g2]
#define WS_TMP    5816576   // [8][2048] (fallback only)
// total ~23.3 MB (d_ws is ~1 GiB per harness fill size)

__device__ __forceinline__ void calc_assign(const float* __restrict__ ws, float a[K0]) {
    float m = -1e30f;
#pragma unroll
    for (int k = 0; k < K0; ++k) { a[k] = -ws[WS_SQ + k] * 0.1f; m = fmaxf(m, a[k]); }
    float s = 0.f;
#pragma unroll
    for (int k = 0; k < K0; ++k) { a[k] = expf(a[k] - m); s += a[k]; }
    float inv = 1.0f / s;
#pragma unroll
    for (int k = 0; k < K0; ++k) a[k] *= inv;
}

// ======================= fused cooperative kernel ===========================
__global__ __launch_bounds__(256, 2) void fused_kernel(
    const float* __restrict__ x,  const float* __restrict__ cc,
    const float* __restrict__ lw, const float* __restrict__ lb,
    const float* __restrict__ wi, const float* __restrict__ bi,
    const float* __restrict__ wn, const float* __restrict__ nb,
    const float* __restrict__ wr, const float* __restrict__ rb,
    float* __restrict__ out, float* __restrict__ ws)
{
    cg::grid_group grid = cg::this_grid();
    __shared__ float smem[2048];   // 8 KB, reused across phases
    const int bid = blockIdx.x, t = threadIdx.x;

    // ---- P0: squared distances ||x - cc[k]||^2, one block per cluster ----
    if (bid < K0) {
        const float4* x4 = (const float4*)x;
        const float4* c4 = (const float4*)(cc + bid * D);
        float acc = 0.f;
#pragma unroll
        for (int i = 0; i < 2; ++i) {
            float4 xv = x4[t + 256 * i], cv = c4[t + 256 * i];
            float dx = xv.x - cv.x, dy = xv.y - cv.y;
            float dz = xv.z - cv.z, dw = xv.w - cv.w;
            acc += dx * dx + dy * dy + dz * dz + dw * dw;
        }
#pragma unroll
        for (int off = 32; off > 0; off >>= 1) acc += __shfl_down(acc, off);
        if ((t & 63) == 0) smem[t >> 6] = acc;
        __syncthreads();
        if (t == 0) ws[WS_SQ + bid] = smem[0] + smem[1] + smem[2] + smem[3];
    }
    grid.sync();

    // Every block recomputes softmax(assign) locally (deterministic).
    float a[K0];
    calc_assign(ws, a);

    // ---- P1: leaf partials, 1024 units (16 k x 2 htile x 32 dchunk) ----
    for (int u = bid; u < 1024; u += NBLK) {
        int k = u >> 6;
        if (a[k] < SKIP_THR) continue;          // block-uniform: skip slab
        int ht = (u >> 5) & 1, dc = u & 31;
        int d0 = dc * 64, h0 = ht * 1024;
        __syncthreads();
        if (t < 64) smem[t] = x[d0 + t];
        __syncthreads();
        int h = h0 + t * 4;
        const float* Wp = lw + ((size_t)k * D + d0) * (size_t)H + h;
        float4 acc = make_float4(0.f, 0.f, 0.f, 0.f);
#pragma unroll 16
        for (int dd = 0; dd < 64; ++dd) {
            float4 w4 = *(const float4*)(Wp + (size_t)dd * H);
            float xv = smem[dd];
            acc.x += xv * w4.x; acc.y += xv * w4.y;
            acc.z += xv * w4.z; acc.w += xv * w4.w;
        }
        *(float4*)(ws + WS_PLEAF + ((size_t)(dc * K0 + k) << 11) + h) = acc;
    }
    grid.sync();

    // ---- P2: c_leaf = assign*tanh(sum+lb), fused with gate softmax ----
    if (bid < K0) {
        const int k = bid;
        const float az = a[k];
        float logit[KJ];
#pragma unroll
        for (int j = 0; j < KJ; ++j) logit[j] = 0.f;
#pragma unroll
        for (int i = 0; i < 8; ++i) {
            int h = t + i * 256;
            float v = 0.f;
            if (az >= SKIP_THR) {
                float s = 0.f;
#pragma unroll
                for (int dc = 0; dc < 32; ++dc)
                    s += ws[WS_PLEAF + ((size_t)(dc * K0 + k) << 11) + h];
                v = tanhf(s + lb[k * H + h]) * az;
            }
            ws[WS_CLEAF + k * H + h] = v;   // zeros for skipped clusters
#pragma unroll
            for (int j = 0; j < KJ; ++j) logit[j] += v * wi[j * H + h];
        }
        __syncthreads();
#pragma unroll
        for (int j = 0; j < KJ; ++j) smem[j * 256 + t] = logit[j];
        __syncthreads();
        for (int s = 128; s > 0; s >>= 1) {
            if (t < s) {
#pragma unroll
                for (int j = 0; j < KJ; ++j)
                    smem[j * 256 + t] += smem[j * 256 + t + s];
            }
            __syncthreads();
        }
        if (t == 0) {
            float l[KJ], m = -1e30f;
#pragma unroll
            for (int j = 0; j < KJ; ++j) { l[j] = smem[j * 256] + bi[j]; m = fmaxf(m, l[j]); }
            float s = 0.f;
#pragma unroll
            for (int j = 0; j < KJ; ++j) { l[j] = expf(l[j] - m); s += l[j]; }
            float inv = 1.0f / s;
#pragma unroll
            for (int j = 0; j < KJ; ++j) ws[WS_GATE + k * KJ + j] = l[j] * inv;
        }
    }
    grid.sync();

    // ---- P3: no-leaf partials, 512 units (8 j x 4 gtile x 16 hchunk) ----
    {
        const int j  = bid >> 6;
        const int gt = (bid >> 4) & 3;
        const int hc = bid & 15;
        for (int i = t; i < K0 * 128; i += 256)
            smem[i] = ws[WS_CLEAF + (i >> 7) * H + hc * 128 + (i & 127)];
        __syncthreads();
        int g = gt * 512 + t * 2;
        const float* Wp = wn + ((size_t)j * H + hc * 128) * (size_t)H + g;
        float2 acc[K0];
#pragma unroll
        for (int k = 0; k < K0; ++k) { acc[k].x = 0.f; acc[k].y = 0.f; }
#pragma unroll 8
        for (int hh = 0; hh < 128; ++hh) {
            float2 w2 = *(const float2*)(Wp + (size_t)hh * H);
#pragma unroll
            for (int k = 0; k < K0; ++k) {
                float c = smem[k * 128 + hh];   // uniform addr = broadcast
                acc[k].x += c * w2.x; acc[k].y += c * w2.y;
            }
        }
#pragma unroll
        for (int k = 0; k < K0; ++k)
            *(float2*)(ws + WS_PNL + ((size_t)((hc * KJ + j) * K0 + k) << 11) + g) = acc[k];
    }
    grid.sync();

    // ---- P4: c_no_leaf[j][g] = sum_k gate[k][j]*tanh(sum_hc pnl + nb) ----
    if (bid < 64) {
        int idx = bid * 256 + t;
        int j = idx >> 11, g = idx & (H - 1);
        float bias = nb[j * H + g];
        float o = 0.f;
#pragma unroll
        for (int k = 0; k < K0; ++k) {
            float s = 0.f;
#pragma unroll
            for (int hc = 0; hc < 16; ++hc)
                s += ws[WS_PNL + ((size_t)((hc * KJ + j) * K0 + k) << 11) + g];
            o += ws[WS_GATE + k * KJ + j] * tanhf(s + bias);
        }
        ws[WS_CNL + j * H + g] = o;
    }
    grid.sync();

    // ---- P5: root partials, 128 units (4 g2tile x 32 gchunk) ----
    if (bid < 128) {
        const int g2t = bid >> 5, gc = bid & 31;
        for (int i = t; i < KJ * 64; i += 256)
            smem[i] = ws[WS_CNL + (i >> 6) * H + gc * 64 + (i & 63)];
        __syncthreads();
        int g2 = g2t * 512 + t * 2;
        float2 acc[KJ];
#pragma unroll
        for (int j = 0; j < KJ; ++j) { acc[j].x = 0.f; acc[j].y = 0.f; }
#pragma unroll 8
        for (int gg = 0; gg < 64; ++gg) {
            float2 w2 = *(const float2*)(wr + (size_t)(gc * 64 + gg) * H + g2);
#pragma unroll
            for (int j = 0; j < KJ; ++j) {
                float c = smem[j * 64 + gg];
                acc[j].x += c * w2.x; acc[j].y += c * w2.y;
            }
        }
#pragma unroll
        for (int j = 0; j < KJ; ++j)
            *(float2*)(ws + WS_PROOT + ((size_t)(gc * KJ + j) << 11) + g2) = acc[j];
    }
    grid.sync();

    // ---- P6: root tanh + sum over j -> out (x2) ----
    if (bid < 16) {
        int g2 = bid * 128 + (t & 127);
        int jh = t >> 7;
        float part = 0.f;
#pragma unroll
        for (int jj = 0; jj < 4; ++jj) {
            int j = jh * 4 + jj;
            float s = 0.f;
#pragma unroll
            for (int gc = 0; gc < 32; ++gc)
                s += ws[WS_PROOT + ((size_t)(gc * KJ + j) << 11) + g2];
            part += tanhf(s + rb[g2]);
        }
        smem[t] = part;
        __syncthreads();
        if (t < 128) {
            float tot = smem[t] + smem[t + 128];
            out[g2] = tot;
            out[H + g2] = tot;
        }
    }
}

// ================= fallback path: proven round-4 pipeline ===================
__global__ void k_assign(const float* __restrict__ x, const float* __restrict__ cc,
                         float* __restrict__ ws) {
    int t = threadIdx.x, w = t >> 6, l = t & 63;   // 1024 thr = 16 waves
    const float4* c4 = (const float4*)(cc + w * D);
    const float4* x4 = (const float4*)x;
    float a = 0.f;
#pragma unroll
    for (int i = 0; i < 8; ++i) {
        float4 xv = x4[l + i * 64];
        float4 cv = c4[l + i * 64];
        float dx = xv.x - cv.x, dy = xv.y - cv.y;
        float dz = xv.z - cv.z, dw = xv.w - cv.w;
        a += dx * dx + dy * dy + dz * dz + dw * dw;
    }
#pragma unroll
    for (int off = 32; off > 0; off >>= 1) a += __shfl_down(a, off);
    __shared__ float sq[K0];
    if (l == 0) sq[w] = a;
    __syncthreads();
    if (t == 0) {
        float v[K0], m = -1e30f;
#pragma unroll
        for (int k = 0; k < K0; ++k) { v[k] = -sq[k] * 0.1f; m = fmaxf(m, v[k]); }
        float s = 0.f;
#pragma unroll
        for (int k = 0; k < K0; ++k) { v[k] = expf(v[k] - m); s += v[k]; }
        float inv = 1.0f / s;
#pragma unroll
        for (int k = 0; k < K0; ++k) ws[WS_SQ + k] = v[k] * inv;   // assign probs
    }
}

__global__ void k_leaf_partial(const float* __restrict__ x, const float* __restrict__ W,
                               float* __restrict__ ws) {
    const int k = blockIdx.x;
    if (ws[WS_SQ + k] < SKIP_THR) return;
    const int h0 = blockIdx.y * 1024;
    const int d0 = blockIdx.z * 64;
    __shared__ float xs[64];
    int t = threadIdx.x;
    if (t < 64) xs[t] = x[d0 + t];
    __syncthreads();
    int h = h0 + t * 4;
    const float* Wp = W + ((size_t)k * D + d0) * (size_t)H + h;
    float4 acc = make_float4(0.f, 0.f, 0.f, 0.f);
#pragma unroll 16
    for (int dd = 0; dd < 64; ++dd) {
        float4 w = *(const float4*)(Wp + (size_t)dd * H);
        float xv = xs[dd];
        acc.x += xv * w.x; acc.y += xv * w.y; acc.z += xv * w.z; acc.w += xv * w.w;
    }
    *(float4*)(ws + WS_PLEAF + ((size_t)(blockIdx.z * K0 + k) << 11) + h) = acc;
}

__global__ void k_cleaf(const float* __restrict__ lb, float* __restrict__ ws) {
    int idx = blockIdx.x * 256 + threadIdx.x;
    int k = idx >> 11, h = idx & (H - 1);
    float az = ws[WS_SQ + k];
    float v = 0.f;
    if (az >= SKIP_THR) {
        float s = 0.f;
#pragma unroll
        for (int dc = 0; dc < 32; ++dc)
            s += ws[WS_PLEAF + ((size_t)(dc * K0 + k) << 11) + h];
        v = tanhf(s + lb[k * H + h]) * az;
    }
    ws[WS_CLEAF + k * H + h] = v;
}

__global__ void k_gate(const float* __restrict__ Wi, const float* __restrict__ bi,
                       float* __restrict__ ws) {
    int k = blockIdx.x;
    int t = threadIdx.x;
    const float* cl = ws + WS_CLEAF + k * H;
    float acc[KJ];
#pragma unroll
    for (int j = 0; j < KJ; ++j) acc[j] = 0.f;
    for (int h = t; h < H; h += 256) {
        float c = cl[h];
#pragma unroll
        for (int j = 0; j < KJ; ++j) acc[j] += c * Wi[j * H + h];
    }
    __shared__ float red[KJ][256];
#pragma unroll
    for (int j = 0; j < KJ; ++j) red[j][t] = acc[j];
    __syncthreads();
    for (int s = 128; s > 0; s >>= 1) {
        if (t < s) {
#pragma unroll
            for (int j = 0; j < KJ; ++j) red[j][t] += red[j][t + s];
        }
        __syncthreads();
    }
    if (t == 0) {
        float l[KJ], m = -1e30f;
#pragma unroll
        for (int j = 0; j < KJ; ++j) { l[j] = red[j][0] + bi[j]; m = fmaxf(m, l[j]); }
        float s = 0.f;
#pragma unroll
        for (int j = 0; j < KJ; ++j) { l[j] = expf(l[j] - m); s += l[j]; }
        float inv = 1.0f / s;
#pragma unroll
        for (int j = 0; j < KJ; ++j) ws[WS_GATE + k * KJ + j] = l[j] * inv;
    }
}

__global__ void k_nl_partial(const float* __restrict__ Wn, float* __restrict__ ws) {
    const int j  = blockIdx.x;
    const int g0 = blockIdx.y * 512;
    const int h0 = blockIdx.z * 128;
    __shared__ float cls[K0][128];
    int t = threadIdx.x;
    for (int i = t; i < K0 * 128; i += 256) {
        int k = i >> 7, hh = i & 127;
        cls[k][hh] = ws[WS_CLEAF + k * H + h0 + hh];
    }
    __syncthreads();
    int g = g0 + t * 2;
    const float* Wp = Wn + ((size_t)j * H + h0) * (size_t)H + g;
    float2 acc[K0];
#pragma unroll
    for (int k = 0; k < K0; ++k) { acc[k].x = 0.f; acc[k].y = 0.f; }
#pragma unroll 8
    for (int hh = 0; hh < 128; ++hh) {
        float2 w = *(const float2*)(Wp + (size_t)hh * H);
#pragma unroll
        for (int k = 0; k < K0; ++k) {
            float c = cls[k][hh];
            acc[k].x += c * w.x; acc[k].y += c * w.y;
        }
    }
#pragma unroll
    for (int k = 0; k < K0; ++k)
        *(float2*)(ws + WS_PNL + ((size_t)((blockIdx.z * KJ + j) * K0 + k) << 11) + g) = acc[k];
}

__global__ void k_cnl(const float* __restrict__ nb, float* __restrict__ ws) {
    int idx = blockIdx.x * 128 + threadIdx.x;
    int j = idx >> 11, g = idx & (H - 1);
    float bias = nb[j * H + g];
    float out = 0.f;
#pragma unroll
    for (int k = 0; k < K0; ++k) {
        float s = 0.f;
#pragma unroll
        for (int hc = 0; hc < 16; ++hc)
            s += ws[WS_PNL + ((size_t)((hc * KJ + j) * K0 + k) << 11) + g];
        out += ws[WS_GATE + k * KJ + j] * tanhf(s + bias);
    }
    ws[WS_CNL + j * H + g] = out;
}

__global__ void k_root_partial(const float* __restrict__ Wr, float* __restrict__ ws) {
    const int g2t = blockIdx.x;
    const int g0  = blockIdx.y * 64;
    __shared__ float cns[KJ][64];
    int t = threadIdx.x;
    for (int i = t; i < KJ * 64; i += 256) {
        int j = i >> 6, gg = i & 63;
        cns[j][gg] = ws[WS_CNL + j * H + g0 + gg];
    }
    __syncthreads();
    int g2 = g2t * 512 + t * 2;
    float2 acc[KJ];
#pragma unroll
    for (int j = 0; j < KJ; ++j) { acc[j].x = 0.f; acc[j].y = 0.f; }
#pragma unroll 8
    for (int gg = 0; gg < 64; ++gg) {
        float2 w = *(const float2*)(Wr + (size_t)(g0 + gg) * H + g2);
#pragma unroll
        for (int j = 0; j < KJ; ++j) {
            float c = cns[j][gg];
            acc[j].x += c * w.x; acc[j].y += c * w.y;
        }
    }
#pragma unroll
    for (int j = 0; j < KJ; ++j)
        *(float2*)(ws + WS_PROOT + ((size_t)(blockIdx.y * KJ + j) << 11) + g2) = acc[j];
}

__global__ void k_root_tanh(const float* __restrict__ rb, float* __restrict__ ws) {
    int j  = blockIdx.x;
    int g2 = blockIdx.y * 256 + threadIdx.x;
    float s = 0.f;
#pragma unroll
    for (int gc = 0; gc < 32; ++gc)
        s += ws[WS_PROOT + ((size_t)(gc * KJ + j) << 11) + g2];
    ws[WS_TMP + j * H + g2] = tanhf(s + rb[g2]);
}

__global__ void k_final(float* __restrict__ ws, float* __restrict__ out) {
    int g2 = blockIdx.x * 256 + threadIdx.x;
    float tot = 0.f;
#pragma unroll
    for (int j = 0; j < KJ; ++j) tot += ws[WS_TMP + j * H + g2];
    out[g2] = tot;
    out[H + g2] = tot;
}

extern "C" void kernel_launch(void* const* d_in, const int* in_sizes, int n_in,
                              void* d_out, int out_size, void* d_ws, size_t ws_size,
                              hipStream_t stream) {
    const float* x  = (const float*)d_in[0];
    const float* cc = (const float*)d_in[1];
    const float* lw = (const float*)d_in[2];
    const float* lb = (const float*)d_in[3];
    const float* wi = (const float*)d_in[4];
    const float* bi = (const float*)d_in[5];
    const float* wn = (const float*)d_in[6];
    const float* nb = (const float*)d_in[7];
    const float* wr = (const float*)d_in[8];
    const float* rb = (const float*)d_in[9];
    float* out = (float*)d_out;
    float* wsf = (float*)d_ws;

    void* args[] = {(void*)&x,  (void*)&cc, (void*)&lw, (void*)&lb,
                    (void*)&wi, (void*)&bi, (void*)&wn, (void*)&nb,
                    (void*)&wr, (void*)&rb, (void*)&out, (void*)&wsf};
    hipError_t e = hipLaunchCooperativeKernel((const void*)fused_kernel,
                                              dim3(NBLK), dim3(256), args, 0, stream);
    if (e != hipSuccess) {
        // Deterministic fallback (same math, round-4-proven): fires every call
        // if cooperative launch is unsupported, so graph capture stays valid.
        k_assign      <<<1, 1024, 0, stream>>>(x, cc, wsf);
        k_leaf_partial<<<dim3(16, 2, 32), 256, 0, stream>>>(x, lw, wsf);
        k_cleaf       <<<128, 256, 0, stream>>>(lb, wsf);
        k_gate        <<<16, 256, 0, stream>>>(wi, bi, wsf);
        k_nl_partial  <<<dim3(8, 4, 16), 256, 0, stream>>>(wn, wsf);
        k_cnl         <<<128, 128, 0, stream>>>(nb, wsf);
        k_root_partial<<<dim3(4, 32), 256, 0, stream>>>(wr, wsf);
        k_root_tanh   <<<dim3(8, 8), 256, 0, stream>>>(rb, wsf);
        k_final       <<<8, 256, 0, stream>>>(wsf, out);
    }
}